// Round 3
// baseline (747.258 us; speedup 1.0000x reference)
//
#include <hip/hip_runtime.h>
#include <cstdint>
#include <cstddef>

// Problem constants (DAC RVQ VAE bottleneck)
constexpr int T   = 4096;
constexpr int BB  = 16;
constexpr int D   = 128;   // INPUT_DIM
constexpr int CB  = 1024;  // CODEBOOK_SIZE
constexpr int CD  = 8;     // CODEBOOK_DIM
constexpr int NCB = 9;     // N_CODEBOOKS

constexpr int TBLK = 32;   // columns (t positions) per block
constexpr int NTHR = 256;  // 4 waves

// Output layout (flat f32 concat, reference return order):
//   z_q [16*128*4096] | kl [1] | commit [1] | cbloss [1] | codes [16*9*4096] | latents [16*72*4096]
constexpr size_t OFF_ZQ    = 0;
constexpr size_t OFF_SCAL  = (size_t)BB * D * T;               // 8388608
constexpr size_t OFF_CODES = OFF_SCAL + 3;                     // 8388611
constexpr size_t OFF_LAT   = OFF_CODES + (size_t)BB * NCB * T; // 8978435

// ---------------------------------------------------------------------------
// Prep: normalize codebook rows (cb / max(||cb||,1e-12)), store 0.5*||cbn||^2,
// and zero the three scalar accumulator slots in d_out.
// ---------------------------------------------------------------------------
__global__ void prep_kernel(const float* __restrict__ codebook,
                            float* __restrict__ cbn,
                            float* __restrict__ h2,
                            float* __restrict__ scal) {
    int e = blockIdx.x * blockDim.x + threadIdx.x;
    if (e == 0) { scal[0] = 0.f; scal[1] = 0.f; scal[2] = 0.f; }
    if (e < NCB * CB) {
        float v[CD];
        float s2 = 0.f;
#pragma unroll
        for (int j = 0; j < CD; ++j) { v[j] = codebook[e * CD + j]; s2 = fmaf(v[j], v[j], s2); }
        float inv = 1.0f / fmaxf(sqrtf(s2), 1e-12f);
        float c2 = 0.f;
#pragma unroll
        for (int j = 0; j < CD; ++j) { float t = v[j] * inv; cbn[e * CD + j] = t; c2 = fmaf(t, t, c2); }
        h2[e] = 0.5f * c2;
    }
}

// ---------------------------------------------------------------------------
// Main fused kernel: one block = 32 consecutive t positions of one batch b.
// 8 blocks/CU resident (19.5 KB LDS, 64 VGPR target) -> 8 waves/SIMD.
// ---------------------------------------------------------------------------
__global__ __launch_bounds__(NTHR, 8)
void rvq_kernel(const float* __restrict__ x,
                const float* __restrict__ noise,
                const float* __restrict__ in_w,
                const float* __restrict__ in_b,
                const float* __restrict__ codebook,
                const float* __restrict__ out_w,
                const float* __restrict__ out_b,
                const float* __restrict__ cbn,
                const float* __restrict__ h2,
                float* __restrict__ o_zq,
                float* __restrict__ o_scal,
                float* __restrict__ o_codes,
                float* __restrict__ o_lat) {
    __shared__ float res[D * TBLK];        // res[d][c], 16 KB
    __shared__ float zen[CD * TBLK];       // raw z_e [j][c], 1 KB
    __shared__ float zqs[CD * TBLK];       // straight-through zq [j][c], 1 KB
    __shared__ float redS[4 * TBLK];       // per-wave best score, 512 B
    __shared__ int   redI[4 * TBLK];       // per-wave best index, 512 B
    __shared__ float redw[8];

    const int tid = threadIdx.x;
    const int c   = tid & 31;            // column within tile
    const int l   = tid & 63;            // lane
    const int s   = tid >> 6;            // wave id
    const int su  = __builtin_amdgcn_readfirstlane(s);
    const int h   = l >> 5;              // lane half (0/1)
    const int col0 = blockIdx.x * TBLK;  // global column = b*T + t
    const int b   = col0 >> 12;
    const int t0  = col0 & 4095;
    const int t   = t0 + c;

    // row ownership for the (d x c) phases: 16 rows per thread
    const int d0  = su * 32 + h * 16;
    // in_proj row (one z_e row per lane-half-of-wave): 8 combos
    const int rin = su + 4 * h;
    // zq-phase row
    const int k2  = 2 * su + h;
    // search mapping: 2 cols per thread, 64-entry chunk
    const int g     = l & 15;            // cols 2g, 2g+1
    const int chunk = su * 4 + (l >> 4); // 16 chunks of 64 entries

    // ---------------- phase 0: vae_sample -> z into res, local KL ----------
    float kl_local = 0.f;
    {
        const float* xm = x     + (size_t)b * 2 * D * T + (size_t)d0 * T + t;
        const float* xs = xm    + (size_t)D * T;
        const float* nz = noise + (size_t)b * D * T     + (size_t)d0 * T + t;
#pragma unroll 4
        for (int k = 0; k < 16; ++k) {
            float m  = xm[(size_t)k * T];
            float sc = xs[(size_t)k * T];
            float nv = nz[(size_t)k * T];
            float sp  = fmaxf(sc, 0.f) + log1pf(expf(-fabsf(sc)));  // softplus
            float sd  = sp + 1e-4f;
            float var = sd * sd;
            float zv  = fmaf(nv, sd, m);
            res[(d0 + k) * TBLK + c] = zv;
            kl_local += m * m + var - logf(var) - 1.0f;
        }
    }
    // kl reduction now (redw reused later for loss)
    {
        float v = kl_local;
#pragma unroll
        for (int o = 32; o > 0; o >>= 1) v += __shfl_down(v, o, 64);
        if (l == 0) redw[s] = v;
        __syncthreads();
        if (tid == 0) {
            float ks = redw[0] + redw[1] + redw[2] + redw[3];
            atomicAdd(&o_scal[0], ks * (1.0f / 65536.0f));  // /(B*T)
        }
    }

    float loss_local = 0.f;

    // ---------------- RVQ loop over 9 codebooks ----------------------------
    for (int i = 0; i < NCB; ++i) {
        __syncthreads();  // res finalized

        // ---- in_proj: one z_e row per (wave, lane-half); all 32 cols ------
        {
            const float4* w4 = (const float4*)(in_w + (size_t)(i * CD + rin) * D);
            float a = in_b[i * CD + rin];
#pragma unroll 8
            for (int k4 = 0; k4 < 32; ++k4) {
                float4 wv = w4[k4];
                a = fmaf(wv.x, res[(k4 * 4 + 0) * TBLK + c], a);
                a = fmaf(wv.y, res[(k4 * 4 + 1) * TBLK + c], a);
                a = fmaf(wv.z, res[(k4 * 4 + 2) * TBLK + c], a);
                a = fmaf(wv.w, res[(k4 * 4 + 3) * TBLK + c], a);
            }
            zen[rin * TBLK + c] = a;
        }
        __syncthreads();

        // ---- search: 2 cols/thread, 64-entry chunk ------------------------
        float e0[CD], e1[CD];
        {
            float n0 = 0.f, n1 = 0.f;
#pragma unroll
            for (int j = 0; j < CD; ++j) {
                e0[j] = zen[j * TBLK + 2 * g];
                e1[j] = zen[j * TBLK + 2 * g + 1];
                n0 = fmaf(e0[j], e0[j], n0);
                n1 = fmaf(e1[j], e1[j], n1);
            }
            float i0 = 1.0f / fmaxf(sqrtf(n0), 1e-12f);
            float i1 = 1.0f / fmaxf(sqrtf(n1), 1e-12f);
#pragma unroll
            for (int j = 0; j < CD; ++j) { e0[j] *= i0; e1[j] *= i1; }
        }

        float best0 = -3.0e38f, best1 = -3.0e38f;
        int   b0 = 0, b1 = 0;
        {
            const float4* cb4 = (const float4*)(cbn + ((size_t)i * CB + chunk * 64) * CD);
            const float*  hb  = h2 + i * CB + chunk * 64;
#pragma unroll 2
            for (int jj = 0; jj < 64; ++jj) {
                float4 ca  = cb4[2 * jj];
                float4 cbv = cb4[2 * jj + 1];
                float  hv  = hb[jj];
                float  s0 = -hv, s1 = -hv;
                s0 = fmaf(ca.x,  e0[0], s0);  s1 = fmaf(ca.x,  e1[0], s1);
                s0 = fmaf(ca.y,  e0[1], s0);  s1 = fmaf(ca.y,  e1[1], s1);
                s0 = fmaf(ca.z,  e0[2], s0);  s1 = fmaf(ca.z,  e1[2], s1);
                s0 = fmaf(ca.w,  e0[3], s0);  s1 = fmaf(ca.w,  e1[3], s1);
                s0 = fmaf(cbv.x, e0[4], s0);  s1 = fmaf(cbv.x, e1[4], s1);
                s0 = fmaf(cbv.y, e0[5], s0);  s1 = fmaf(cbv.y, e1[5], s1);
                s0 = fmaf(cbv.z, e0[6], s0);  s1 = fmaf(cbv.z, e1[6], s1);
                s0 = fmaf(cbv.w, e0[7], s0);  s1 = fmaf(cbv.w, e1[7], s1);
                if (s0 > best0) { best0 = s0; b0 = jj; }  // strict > : first idx
                if (s1 > best1) { best1 = s1; b1 = jj; }
            }
        }
        b0 += chunk * 64;
        b1 += chunk * 64;

        // merge the 4 chunks per col held by lanes l, l+16, l+32, l+48
        {
            float o; int oi;
            o = __shfl_down(best0, 16, 64); oi = __shfl_down(b0, 16, 64);
            if (o > best0) { best0 = o; b0 = oi; }
            o = __shfl_down(best1, 16, 64); oi = __shfl_down(b1, 16, 64);
            if (o > best1) { best1 = o; b1 = oi; }
            o = __shfl_down(best0, 32, 64); oi = __shfl_down(b0, 32, 64);
            if (o > best0) { best0 = o; b0 = oi; }
            o = __shfl_down(best1, 32, 64); oi = __shfl_down(b1, 32, 64);
            if (o > best1) { best1 = o; b1 = oi; }
        }
        if (l < 16) {
            redS[s * TBLK + 2 * g]     = best0;
            redI[s * TBLK + 2 * g]     = b0;
            redS[s * TBLK + 2 * g + 1] = best1;
            redI[s * TBLK + 2 * g + 1] = b1;
        }
        __syncthreads();

        // final reduce across 4 waves (ascending wave = ascending entry range)
        float bsc = redS[c];
        int   bi  = redI[c];
#pragma unroll
        for (int ww = 1; ww < 4; ++ww) {
            float v2 = redS[ww * TBLK + c];
            int   vi = redI[ww * TBLK + c];
            if (v2 > bsc) { bsc = v2; bi = vi; }
        }
        if (tid < 32) o_codes[(size_t)b * NCB * T + (size_t)i * T + t0 + tid] = (float)bi;

        // ---- zq + latents + loss: one (k,c) per thread --------------------
        {
            float ze = zen[k2 * TBLK + c];
            o_lat[(size_t)b * (NCB * CD) * T + (size_t)(i * CD + k2) * T + t] = ze;
            float cv = codebook[((size_t)i * CB + bi) * CD + k2];
            float dd = cv - ze;
            loss_local = fmaf(dd, dd, loss_local);
            zqs[k2 * TBLK + c] = ze + dd;   // zq_st = z_e + (c - z_e), reference rounding
        }
        __syncthreads();

        // ---- out_proj + residual update: 16 rows/thread -------------------
        {
            float zqv[CD];
#pragma unroll
            for (int j = 0; j < CD; ++j) zqv[j] = zqs[j * TBLK + c];
            const float4* ow4 = (const float4*)(out_w + ((size_t)i * D + d0) * CD);
            const float*  ob  = out_b + (size_t)i * D + d0;
#pragma unroll 4
            for (int m = 0; m < 16; ++m) {
                float4 wa = ow4[2 * m];
                float4 wb = ow4[2 * m + 1];
                float acc = ob[m];
                acc = fmaf(wa.x, zqv[0], acc);
                acc = fmaf(wa.y, zqv[1], acc);
                acc = fmaf(wa.z, zqv[2], acc);
                acc = fmaf(wa.w, zqv[3], acc);
                acc = fmaf(wb.x, zqv[4], acc);
                acc = fmaf(wb.y, zqv[5], acc);
                acc = fmaf(wb.z, zqv[6], acc);
                acc = fmaf(wb.w, zqv[7], acc);
                res[(d0 + m) * TBLK + c] -= acc;   // unique owner per (d,c)
            }
        }
    }
    __syncthreads();

    // ---------------- final: z_q = z - residual (recompute z) --------------
    {
        const float* xm = x     + (size_t)b * 2 * D * T + (size_t)d0 * T + t;
        const float* xs = xm    + (size_t)D * T;
        const float* nz = noise + (size_t)b * D * T     + (size_t)d0 * T + t;
        float*       oq = o_zq  + (size_t)b * D * T     + (size_t)d0 * T + t;
#pragma unroll 4
        for (int k = 0; k < 16; ++k) {
            float m  = xm[(size_t)k * T];
            float sc = xs[(size_t)k * T];
            float nv = nz[(size_t)k * T];
            float sp = fmaxf(sc, 0.f) + log1pf(expf(-fabsf(sc)));
            float sd = sp + 1e-4f;
            float zv = fmaf(nv, sd, m);
            oq[(size_t)k * T] = zv - res[(d0 + k) * TBLK + c];
        }
    }

    // ---------------- loss reduction ---------------------------------------
    {
        float w2 = loss_local;
#pragma unroll
        for (int o = 32; o > 0; o >>= 1) w2 += __shfl_down(w2, o, 64);
        if (l == 0) redw[4 + s] = w2;
        __syncthreads();
        if (tid == 0) {
            float ls = redw[4] + redw[5] + redw[6] + redw[7];
            float lsn = ls * (1.0f / (524288.0f * 9.0f));   // /(B*8*T)/NCB
            atomicAdd(&o_scal[1], lsn);                     // commitment
            atomicAdd(&o_scal[2], lsn);                     // codebook (identical in eval)
        }
    }
}

extern "C" void kernel_launch(void* const* d_in, const int* in_sizes, int n_in,
                              void* d_out, int out_size, void* d_ws, size_t ws_size,
                              hipStream_t stream) {
    const float* x        = (const float*)d_in[0];
    const float* noise    = (const float*)d_in[1];
    const float* in_w     = (const float*)d_in[2];
    const float* in_b     = (const float*)d_in[3];
    const float* codebook = (const float*)d_in[4];
    const float* out_w    = (const float*)d_in[5];
    const float* out_b    = (const float*)d_in[6];

    float* out     = (float*)d_out;
    float* o_zq    = out + OFF_ZQ;
    float* o_scal  = out + OFF_SCAL;
    float* o_codes = out + OFF_CODES;
    float* o_lat   = out + OFF_LAT;

    // workspace: normalized codebook + half squared norms
    float* cbn = (float*)d_ws;                 // 9*1024*8 floats
    float* h2  = cbn + (size_t)NCB * CB * CD;  // 9*1024 floats

    prep_kernel<<<(NCB * CB + 255) / 256, 256, 0, stream>>>(codebook, cbn, h2, o_scal);

    dim3 grid(BB * (T / TBLK));  // 16 * 128 = 2048 blocks
    rvq_kernel<<<grid, NTHR, 0, stream>>>(x, noise, in_w, in_b, codebook, out_w, out_b,
                                          cbn, h2, o_zq, o_scal, o_codes, o_lat);
}

// Round 4
// 743.710 us; speedup vs baseline: 1.0048x; 1.0048x over previous
//
#include <hip/hip_runtime.h>
#include <cstdint>
#include <cstddef>

// Problem constants (DAC RVQ VAE bottleneck)
constexpr int T   = 4096;
constexpr int BB  = 16;
constexpr int D   = 128;   // INPUT_DIM
constexpr int CB  = 1024;  // CODEBOOK_SIZE
constexpr int CD  = 8;     // CODEBOOK_DIM
constexpr int NCB = 9;     // N_CODEBOOKS

constexpr int TBLK = 32;   // columns (t positions) per block
constexpr int NTHR = 256;  // 4 waves

// Output layout (flat f32 concat, reference return order):
//   z_q [16*128*4096] | kl [1] | commit [1] | cbloss [1] | codes [16*9*4096] | latents [16*72*4096]
constexpr size_t OFF_ZQ    = 0;
constexpr size_t OFF_SCAL  = (size_t)BB * D * T;               // 8388608
constexpr size_t OFF_CODES = OFF_SCAL + 3;                     // 8388611
constexpr size_t OFF_LAT   = OFF_CODES + (size_t)BB * NCB * T; // 8978435

// ---------------------------------------------------------------------------
// Prep: normalize codebook rows (cb / max(||cb||,1e-12)), store 0.5*||cbn||^2,
// and zero the three scalar accumulator slots in d_out.
// ---------------------------------------------------------------------------
__global__ void prep_kernel(const float* __restrict__ codebook,
                            float* __restrict__ cbn,
                            float* __restrict__ h2,
                            float* __restrict__ scal) {
    int e = blockIdx.x * blockDim.x + threadIdx.x;
    if (e == 0) { scal[0] = 0.f; scal[1] = 0.f; scal[2] = 0.f; }
    if (e < NCB * CB) {
        float v[CD];
        float s2 = 0.f;
#pragma unroll
        for (int j = 0; j < CD; ++j) { v[j] = codebook[e * CD + j]; s2 = fmaf(v[j], v[j], s2); }
        float inv = 1.0f / fmaxf(sqrtf(s2), 1e-12f);
        float c2 = 0.f;
#pragma unroll
        for (int j = 0; j < CD; ++j) { float t = v[j] * inv; cbn[e * CD + j] = t; c2 = fmaf(t, t, c2); }
        h2[e] = 0.5f * c2;
    }
}

// ---------------------------------------------------------------------------
// Main fused kernel: one block = 32 consecutive t positions of one batch b.
// launch_bounds(256,6): VGPR cap ~85 (no spill), 6 blocks/CU (23.6 KB LDS).
// ---------------------------------------------------------------------------
__global__ __launch_bounds__(NTHR, 6)
void rvq_kernel(const float* __restrict__ x,
                const float* __restrict__ noise,
                const float* __restrict__ in_w,
                const float* __restrict__ in_b,
                const float* __restrict__ codebook,
                const float* __restrict__ out_w,
                const float* __restrict__ out_b,
                const float* __restrict__ cbn,
                const float* __restrict__ h2,
                float* __restrict__ o_zq,
                float* __restrict__ o_scal,
                float* __restrict__ o_codes,
                float* __restrict__ o_lat) {
    __shared__ float res[D * TBLK];        // res[d][c], 16 KB
    __shared__ float pbuf[4 * CD * TBLK];  // in_proj partials [wave][j][c], 4 KB
    __shared__ float zen[CD * TBLK];       // raw z_e [j][c], 1 KB
    __shared__ float zqs[CD * TBLK];       // straight-through zq [j][c], 1 KB
    __shared__ float redS[4 * TBLK];       // per-wave best score, 512 B
    __shared__ int   redI[4 * TBLK];       // per-wave best index, 512 B
    __shared__ float redw[8];

    const int tid = threadIdx.x;
    const int c   = tid & 31;            // column within tile
    const int l   = tid & 63;            // lane
    const int s   = tid >> 6;            // wave id
    const int su  = __builtin_amdgcn_readfirstlane(s);
    const int h   = l >> 5;              // lane half (0/1)
    const int col0 = blockIdx.x * TBLK;  // global column = b*T + t
    const int b   = col0 >> 12;
    const int t0  = col0 & 4095;
    const int t   = t0 + c;

    // (d x c) phases: 16 rows per thread
    const int d0  = su * 32 + h * 16;
    // in_proj split-k: k-group of 16 per thread
    const int q   = tid >> 5;            // 0..7, = 2*su + h
    // zen reduce / zq phase: one (row j, col c) per thread
    const int jr  = tid >> 5;            // 0..7
    // search mapping: 2 cols per thread, 64-entry chunk
    const int g     = l & 15;            // cols 2g, 2g+1
    const int chunk = su * 4 + (l >> 4); // 16 chunks of 64 entries

    // ---------------- phase 0: vae_sample -> z into res, local KL ----------
    float kl_local = 0.f;
    {
        const float* xm = x     + (size_t)b * 2 * D * T + (size_t)d0 * T + t;
        const float* xs = xm    + (size_t)D * T;
        const float* nz = noise + (size_t)b * D * T     + (size_t)d0 * T + t;
#pragma unroll 4
        for (int k = 0; k < 16; ++k) {
            float m  = xm[(size_t)k * T];
            float sc = xs[(size_t)k * T];
            float nv = nz[(size_t)k * T];
            float sp  = fmaxf(sc, 0.f) + log1pf(expf(-fabsf(sc)));  // softplus
            float sd  = sp + 1e-4f;
            float var = sd * sd;
            float zv  = fmaf(nv, sd, m);
            res[(d0 + k) * TBLK + c] = zv;
            kl_local += m * m + var - logf(var) - 1.0f;
        }
    }
    // kl reduction (redw slots 0..3)
    {
        float v = kl_local;
#pragma unroll
        for (int o = 32; o > 0; o >>= 1) v += __shfl_down(v, o, 64);
        if (l == 0) redw[s] = v;
        __syncthreads();
        if (tid == 0) {
            float ks = redw[0] + redw[1] + redw[2] + redw[3];
            atomicAdd(&o_scal[0], ks * (1.0f / 65536.0f));  // /(B*T)
        }
    }

    float loss_local = 0.f;

    // ---------------- RVQ loop over 9 codebooks ----------------------------
    for (int i = 0; i < NCB; ++i) {
        __syncthreads();  // res finalized (phase 0 or previous out_proj)

        // ---- in_proj split-k: thread (q,c) covers k in [16q,16q+16) -------
        {
            float r[16];
#pragma unroll
            for (int kk = 0; kk < 16; ++kk) r[kk] = res[(q * 16 + kk) * TBLK + c];

            float p[CD];
            const float4* w4 = (const float4*)(in_w + (size_t)i * CD * D + q * 16);
#pragma unroll
            for (int j = 0; j < CD; ++j) {
                // row j, k = 16q .. 16q+15 (ascending)
                float4 wa = w4[j * 32 + 0];
                float4 wb = w4[j * 32 + 1];
                float4 wc = w4[j * 32 + 2];
                float4 wd = w4[j * 32 + 3];
                float a = 0.f;
                a = fmaf(wa.x, r[0],  a); a = fmaf(wa.y, r[1],  a);
                a = fmaf(wa.z, r[2],  a); a = fmaf(wa.w, r[3],  a);
                a = fmaf(wb.x, r[4],  a); a = fmaf(wb.y, r[5],  a);
                a = fmaf(wb.z, r[6],  a); a = fmaf(wb.w, r[7],  a);
                a = fmaf(wc.x, r[8],  a); a = fmaf(wc.y, r[9],  a);
                a = fmaf(wc.z, r[10], a); a = fmaf(wc.w, r[11], a);
                a = fmaf(wd.x, r[12], a); a = fmaf(wd.y, r[13], a);
                a = fmaf(wd.z, r[14], a); a = fmaf(wd.w, r[15], a);
                p[j] = a;
            }
            // fold the two halves of the wave (q=2s and q=2s+1)
#pragma unroll
            for (int j = 0; j < CD; ++j) p[j] += __shfl_down(p[j], 32, 64);
            if (h == 0) {
#pragma unroll
                for (int j = 0; j < CD; ++j) pbuf[(s * CD + j) * TBLK + c] = p[j];
            }
        }
        __syncthreads();

        // ---- reduce partials -> z_e; write zen + latents ------------------
        {
            float ze = in_b[i * CD + jr];
            ze += pbuf[(0 * CD + jr) * TBLK + c];
            ze += pbuf[(1 * CD + jr) * TBLK + c];
            ze += pbuf[(2 * CD + jr) * TBLK + c];
            ze += pbuf[(3 * CD + jr) * TBLK + c];
            zen[jr * TBLK + c] = ze;
            o_lat[(size_t)b * (NCB * CD) * T + (size_t)(i * CD + jr) * T + t] = ze;
        }
        __syncthreads();

        // ---- search: 2 cols/thread, 64-entry chunk ------------------------
        float e0[CD], e1[CD];
        {
            float n0 = 0.f, n1 = 0.f;
#pragma unroll
            for (int j = 0; j < CD; ++j) {
                e0[j] = zen[j * TBLK + 2 * g];
                e1[j] = zen[j * TBLK + 2 * g + 1];
                n0 = fmaf(e0[j], e0[j], n0);
                n1 = fmaf(e1[j], e1[j], n1);
            }
            float i0 = 1.0f / fmaxf(sqrtf(n0), 1e-12f);
            float i1 = 1.0f / fmaxf(sqrtf(n1), 1e-12f);
#pragma unroll
            for (int j = 0; j < CD; ++j) { e0[j] *= i0; e1[j] *= i1; }
        }

        float best0 = -3.0e38f, best1 = -3.0e38f;
        int   b0 = 0, b1 = 0;
        {
            const float4* cb4 = (const float4*)(cbn + ((size_t)i * CB + chunk * 64) * CD);
            const float*  hb  = h2 + i * CB + chunk * 64;
#pragma unroll 2
            for (int jj = 0; jj < 64; ++jj) {
                float4 ca  = cb4[2 * jj];
                float4 cbv = cb4[2 * jj + 1];
                float  hv  = hb[jj];
                float  s0 = -hv, s1 = -hv;
                s0 = fmaf(ca.x,  e0[0], s0);  s1 = fmaf(ca.x,  e1[0], s1);
                s0 = fmaf(ca.y,  e0[1], s0);  s1 = fmaf(ca.y,  e1[1], s1);
                s0 = fmaf(ca.z,  e0[2], s0);  s1 = fmaf(ca.z,  e1[2], s1);
                s0 = fmaf(ca.w,  e0[3], s0);  s1 = fmaf(ca.w,  e1[3], s1);
                s0 = fmaf(cbv.x, e0[4], s0);  s1 = fmaf(cbv.x, e1[4], s1);
                s0 = fmaf(cbv.y, e0[5], s0);  s1 = fmaf(cbv.y, e1[5], s1);
                s0 = fmaf(cbv.z, e0[6], s0);  s1 = fmaf(cbv.z, e1[6], s1);
                s0 = fmaf(cbv.w, e0[7], s0);  s1 = fmaf(cbv.w, e1[7], s1);
                if (s0 > best0) { best0 = s0; b0 = jj; }  // strict > : first idx
                if (s1 > best1) { best1 = s1; b1 = jj; }
            }
        }
        b0 += chunk * 64;
        b1 += chunk * 64;

        // merge the 4 chunks per col held by lanes l, l+16, l+32, l+48
        {
            float o; int oi;
            o = __shfl_down(best0, 16, 64); oi = __shfl_down(b0, 16, 64);
            if (o > best0) { best0 = o; b0 = oi; }
            o = __shfl_down(best1, 16, 64); oi = __shfl_down(b1, 16, 64);
            if (o > best1) { best1 = o; b1 = oi; }
            o = __shfl_down(best0, 32, 64); oi = __shfl_down(b0, 32, 64);
            if (o > best0) { best0 = o; b0 = oi; }
            o = __shfl_down(best1, 32, 64); oi = __shfl_down(b1, 32, 64);
            if (o > best1) { best1 = o; b1 = oi; }
        }
        if (l < 16) {
            redS[s * TBLK + 2 * g]     = best0;
            redI[s * TBLK + 2 * g]     = b0;
            redS[s * TBLK + 2 * g + 1] = best1;
            redI[s * TBLK + 2 * g + 1] = b1;
        }
        __syncthreads();

        // final reduce across 4 waves (ascending wave = ascending entry range)
        float bsc = redS[c];
        int   bi  = redI[c];
#pragma unroll
        for (int ww = 1; ww < 4; ++ww) {
            float v2 = redS[ww * TBLK + c];
            int   vi = redI[ww * TBLK + c];
            if (v2 > bsc) { bsc = v2; bi = vi; }
        }
        if (tid < 32) o_codes[(size_t)b * NCB * T + (size_t)i * T + t0 + tid] = (float)bi;

        // ---- zq + loss: one (jr,c) per thread -----------------------------
        {
            float ze = zen[jr * TBLK + c];
            float cv = codebook[((size_t)i * CB + bi) * CD + jr];
            float dd = cv - ze;
            loss_local = fmaf(dd, dd, loss_local);
            zqs[jr * TBLK + c] = ze + dd;   // zq_st = z_e + (c - z_e), reference rounding
        }
        __syncthreads();

        // ---- out_proj + residual update: 16 rows/thread -------------------
        {
            float zqv[CD];
#pragma unroll
            for (int j = 0; j < CD; ++j) zqv[j] = zqs[j * TBLK + c];
            const float4* ow4 = (const float4*)(out_w + ((size_t)i * D + d0) * CD);
            const float*  ob  = out_b + (size_t)i * D + d0;
#pragma unroll 4
            for (int m = 0; m < 16; ++m) {
                float4 wa = ow4[2 * m];
                float4 wb = ow4[2 * m + 1];
                float acc = ob[m];
                acc = fmaf(wa.x, zqv[0], acc);
                acc = fmaf(wa.y, zqv[1], acc);
                acc = fmaf(wa.z, zqv[2], acc);
                acc = fmaf(wa.w, zqv[3], acc);
                acc = fmaf(wb.x, zqv[4], acc);
                acc = fmaf(wb.y, zqv[5], acc);
                acc = fmaf(wb.z, zqv[6], acc);
                acc = fmaf(wb.w, zqv[7], acc);
                res[(d0 + m) * TBLK + c] -= acc;   // unique owner per (d,c)
            }
        }
    }
    __syncthreads();

    // ---------------- final: z_q = z - residual (recompute z) --------------
    {
        const float* xm = x     + (size_t)b * 2 * D * T + (size_t)d0 * T + t;
        const float* xs = xm    + (size_t)D * T;
        const float* nz = noise + (size_t)b * D * T     + (size_t)d0 * T + t;
        float*       oq = o_zq  + (size_t)b * D * T     + (size_t)d0 * T + t;
#pragma unroll 4
        for (int k = 0; k < 16; ++k) {
            float m  = xm[(size_t)k * T];
            float sc = xs[(size_t)k * T];
            float nv = nz[(size_t)k * T];
            float sp = fmaxf(sc, 0.f) + log1pf(expf(-fabsf(sc)));
            float sd = sp + 1e-4f;
            float zv = fmaf(nv, sd, m);
            oq[(size_t)k * T] = zv - res[(d0 + k) * TBLK + c];
        }
    }

    // ---------------- loss reduction ---------------------------------------
    {
        float w2 = loss_local;
#pragma unroll
        for (int o = 32; o > 0; o >>= 1) w2 += __shfl_down(w2, o, 64);
        if (l == 0) redw[4 + s] = w2;
        __syncthreads();
        if (tid == 0) {
            float ls = redw[4] + redw[5] + redw[6] + redw[7];
            float lsn = ls * (1.0f / (524288.0f * 9.0f));   // /(B*8*T)/NCB
            atomicAdd(&o_scal[1], lsn);                     // commitment
            atomicAdd(&o_scal[2], lsn);                     // codebook (identical in eval)
        }
    }
}

extern "C" void kernel_launch(void* const* d_in, const int* in_sizes, int n_in,
                              void* d_out, int out_size, void* d_ws, size_t ws_size,
                              hipStream_t stream) {
    const float* x        = (const float*)d_in[0];
    const float* noise    = (const float*)d_in[1];
    const float* in_w     = (const float*)d_in[2];
    const float* in_b     = (const float*)d_in[3];
    const float* codebook = (const float*)d_in[4];
    const float* out_w    = (const float*)d_in[5];
    const float* out_b    = (const float*)d_in[6];

    float* out     = (float*)d_out;
    float* o_zq    = out + OFF_ZQ;
    float* o_scal  = out + OFF_SCAL;
    float* o_codes = out + OFF_CODES;
    float* o_lat   = out + OFF_LAT;

    // workspace: normalized codebook + half squared norms
    float* cbn = (float*)d_ws;                 // 9*1024*8 floats
    float* h2  = cbn + (size_t)NCB * CB * CD;  // 9*1024 floats

    prep_kernel<<<(NCB * CB + 255) / 256, 256, 0, stream>>>(codebook, cbn, h2, o_scal);

    dim3 grid(BB * (T / TBLK));  // 16 * 128 = 2048 blocks
    rvq_kernel<<<grid, NTHR, 0, stream>>>(x, noise, in_w, in_b, codebook, out_w, out_b,
                                          cbn, h2, o_zq, o_scal, o_codes, o_lat);
}

// Round 5
// 735.741 us; speedup vs baseline: 1.0157x; 1.0108x over previous
//
#include <hip/hip_runtime.h>
#include <cstdint>
#include <cstddef>

// Problem constants (DAC RVQ VAE bottleneck)
constexpr int T   = 4096;
constexpr int BB  = 16;
constexpr int D   = 128;   // INPUT_DIM
constexpr int CB  = 1024;  // CODEBOOK_SIZE
constexpr int CD  = 8;     // CODEBOOK_DIM
constexpr int NCB = 9;     // N_CODEBOOKS
constexpr int NP  = 36;    // pairs (i,j), j<i

constexpr int TBLK = 32;   // columns per block
constexpr int NTHR = 256;  // 4 waves

// Output layout (flat f32 concat, reference return order):
//   z_q [16*128*4096] | kl | commit | cbloss | codes [16*9*4096] | latents [16*72*4096]
constexpr size_t OFF_ZQ    = 0;
constexpr size_t OFF_SCAL  = (size_t)BB * D * T;               // 8388608
constexpr size_t OFF_CODES = OFF_SCAL + 3;                     // 8388611
constexpr size_t OFF_LAT   = OFF_CODES + (size_t)BB * NCB * T; // 8978435

// workspace float offsets
constexpr size_t WS_CBN = 0;                              // 9*1024*8
constexpr size_t WS_H2  = WS_CBN + (size_t)NCB * CB * CD; // 9*1024
constexpr size_t WS_G   = WS_H2 + (size_t)NCB * CB;       // 36*64
constexpr size_t WS_U   = WS_G + (size_t)NP * 64;         // 36*8
constexpr size_t WS_OBS = WS_U + (size_t)NP * 8;          // 128

// ---------------------------------------------------------------------------
// Prep 1: normalized codebook + 0.5*||cbn||^2; zero scalar slots.
// ---------------------------------------------------------------------------
__global__ void prep_kernel(const float* __restrict__ codebook,
                            float* __restrict__ cbn,
                            float* __restrict__ h2,
                            float* __restrict__ scal) {
    int e = blockIdx.x * blockDim.x + threadIdx.x;
    if (e == 0) { scal[0] = 0.f; scal[1] = 0.f; scal[2] = 0.f; }
    if (e < NCB * CB) {
        float v[CD];
        float s2 = 0.f;
#pragma unroll
        for (int j = 0; j < CD; ++j) { v[j] = codebook[e * CD + j]; s2 = fmaf(v[j], v[j], s2); }
        float inv = 1.0f / fmaxf(sqrtf(s2), 1e-12f);
        float c2 = 0.f;
#pragma unroll
        for (int j = 0; j < CD; ++j) { float t = v[j] * inv; cbn[e * CD + j] = t; c2 = fmaf(t, t, c2); }
        h2[e] = 0.5f * c2;
    }
}

// ---------------------------------------------------------------------------
// Prep 2: coupling matrices G[p][r][k] = in_w[i][r]@out_w[j][:, k]  (p=(i,j), j<i)
//         u[p][r] = in_w[i][r]@out_b[j];  obs[d] = sum_j out_b[j][d]
// ---------------------------------------------------------------------------
__global__ void prep2_kernel(const float* __restrict__ in_w,
                             const float* __restrict__ out_w,
                             const float* __restrict__ out_b,
                             float* __restrict__ G,
                             float* __restrict__ u,
                             float* __restrict__ obs) {
    int id = blockIdx.x * blockDim.x + threadIdx.x;
    if (id < NP * 64) {
        int p = id >> 6;
        int r = (id >> 3) & 7;
        int k = id & 7;
        int i = 1; while (i * (i + 1) / 2 <= p) ++i;
        int j = p - i * (i - 1) / 2;
        const float* wi = in_w  + (size_t)(i * CD + r) * D;
        const float* wo = out_w + (size_t)j * D * CD + k;
        float a = 0.f;
        for (int d = 0; d < D; ++d) a = fmaf(wi[d], wo[(size_t)d * CD], a);
        G[p * 64 + r * 8 + k] = a;
    } else if (id < NP * 64 + NP * 8) {
        int q = id - NP * 64;
        int p = q >> 3, r = q & 7;
        int i = 1; while (i * (i + 1) / 2 <= p) ++i;
        int j = p - i * (i - 1) / 2;
        const float* wi = in_w  + (size_t)(i * CD + r) * D;
        const float* ob = out_b + (size_t)j * D;
        float a = 0.f;
        for (int d = 0; d < D; ++d) a = fmaf(wi[d], ob[d], a);
        u[p * 8 + r] = a;
    } else if (id < NP * 64 + NP * 8 + D) {
        int d = id - (NP * 64 + NP * 8);
        float a = 0.f;
        for (int j = 0; j < NCB; ++j) a += out_b[(size_t)j * D + d];
        obs[d] = a;
    }
}

// ---------------------------------------------------------------------------
// Main fused kernel (telescoped RVQ). One block = 32 t-positions of batch b.
// ---------------------------------------------------------------------------
__global__ __launch_bounds__(NTHR)
void rvq_kernel(const float* __restrict__ x,
                const float* __restrict__ noise,
                const float* __restrict__ in_w,
                const float* __restrict__ in_b,
                const float* __restrict__ codebook,
                const float* __restrict__ out_w,
                const float* __restrict__ cbn,
                const float* __restrict__ h2,
                const float* __restrict__ G,
                const float* __restrict__ u,
                const float* __restrict__ obs,
                float* __restrict__ o_zq,
                float* __restrict__ o_scal,
                float* __restrict__ o_codes,
                float* __restrict__ o_lat) {
    __shared__ float zz[D * TBLK];        // z tile (phase A/B); then zq history [72][TBLK]
    __shared__ float Pt[72 * TBLK];       // P rows [72][TBLK] (live all kernel)
    __shared__ float redS[4 * TBLK];
    __shared__ int   redI[4 * TBLK];
    __shared__ float redw[8];
    float* zh = zz;                       // zq history overlays z (9216 <= 16384 floats)

    const int tid = threadIdx.x;
    const int c   = tid & 31;            // column
    const int l   = tid & 63;            // lane
    const int s   = tid >> 6;            // wave
    const int su  = __builtin_amdgcn_readfirstlane(s);
    const int h   = l >> 5;              // lane half
    const int col0 = blockIdx.x * TBLK;
    const int b   = col0 >> 12;
    const int t0  = col0 & 4095;
    const int t   = t0 + c;

    const int d0  = su * 32 + h * 16;    // 16 rows per thread (phase A, final)
    const int r   = tid >> 5;            // 0..7 (phase B, zq, P-update)
    const int g     = l & 15;            // search: cols 2g, 2g+1
    const int chunk = su * 4 + (l >> 4); // search: 64-entry chunk

    // ---------------- phase A: vae_sample -> z into zz, KL -----------------
    float kl_local = 0.f;
    {
        const float* xm = x     + (size_t)b * 2 * D * T + (size_t)d0 * T + t;
        const float* xs = xm    + (size_t)D * T;
        const float* nz = noise + (size_t)b * D * T     + (size_t)d0 * T + t;
#pragma unroll 4
        for (int k = 0; k < 16; ++k) {
            float m  = xm[(size_t)k * T];
            float sc = xs[(size_t)k * T];
            float nv = nz[(size_t)k * T];
            float sp  = fmaxf(sc, 0.f) + log1pf(expf(-fabsf(sc)));  // softplus
            float sd  = sp + 1e-4f;
            float var = sd * sd;
            kl_local += m * m + var - logf(var) - 1.0f;
            zz[(d0 + k) * TBLK + c] = fmaf(nv, sd, m);
        }
#pragma unroll
        for (int o = 32; o > 0; o >>= 1) kl_local += __shfl_down(kl_local, o, 64);
        if (l == 0) redw[s] = kl_local;
    }
    __syncthreads();   // zz + redw ready
    if (tid == 0) {
        float ks = redw[0] + redw[1] + redw[2] + redw[3];
        atomicAdd(&o_scal[0], ks * (1.0f / 65536.0f));
    }

    // ---------------- phase B: P[i*8+r] = in_w[i][r]@z + in_b  -------------
    {
        float acc[NCB];
#pragma unroll
        for (int i = 0; i < NCB; ++i) acc[i] = in_b[i * CD + r];
        const float4* iw4 = (const float4*)in_w;
#pragma unroll 4
        for (int k4 = 0; k4 < 32; ++k4) {
            float z0 = zz[(k4 * 4 + 0) * TBLK + c];
            float z1 = zz[(k4 * 4 + 1) * TBLK + c];
            float z2 = zz[(k4 * 4 + 2) * TBLK + c];
            float z3 = zz[(k4 * 4 + 3) * TBLK + c];
#pragma unroll
            for (int i = 0; i < NCB; ++i) {
                float4 w = iw4[(size_t)(i * CD + r) * 32 + k4];
                acc[i] = fmaf(w.x, z0, acc[i]);
                acc[i] = fmaf(w.y, z1, acc[i]);
                acc[i] = fmaf(w.z, z2, acc[i]);
                acc[i] = fmaf(w.w, z3, acc[i]);
            }
        }
#pragma unroll
        for (int i = 0; i < NCB; ++i) Pt[(i * CD + r) * TBLK + c] = acc[i];
    }
    __syncthreads();   // Pt ready; zz reads done (zh overlay now legal)

    float loss_local = 0.f;

    // ---------------- RVQ loop: pure 8-dim space ---------------------------
    for (int i = 0; i < NCB; ++i) {
        const int base = i * CD;

        // ---- search: 2 cols/thread, 64-entry chunk (reads Pt rows i) ------
        float e0[CD], e1[CD];
        {
            float n0 = 0.f, n1 = 0.f;
#pragma unroll
            for (int j = 0; j < CD; ++j) {
                e0[j] = Pt[(base + j) * TBLK + 2 * g];
                e1[j] = Pt[(base + j) * TBLK + 2 * g + 1];
                n0 = fmaf(e0[j], e0[j], n0);
                n1 = fmaf(e1[j], e1[j], n1);
            }
            float i0 = 1.0f / fmaxf(sqrtf(n0), 1e-12f);
            float i1 = 1.0f / fmaxf(sqrtf(n1), 1e-12f);
#pragma unroll
            for (int j = 0; j < CD; ++j) { e0[j] *= i0; e1[j] *= i1; }
        }

        float best0 = -3.0e38f, best1 = -3.0e38f;
        int   b0 = 0, b1 = 0;
        {
            const float4* cb4 = (const float4*)(cbn + ((size_t)i * CB + chunk * 64) * CD);
            const float*  hb  = h2 + i * CB + chunk * 64;
#pragma unroll 2
            for (int jj = 0; jj < 64; ++jj) {
                float4 ca  = cb4[2 * jj];
                float4 cbv = cb4[2 * jj + 1];
                float  hv  = hb[jj];
                float  s0 = -hv, s1 = -hv;
                s0 = fmaf(ca.x,  e0[0], s0);  s1 = fmaf(ca.x,  e1[0], s1);
                s0 = fmaf(ca.y,  e0[1], s0);  s1 = fmaf(ca.y,  e1[1], s1);
                s0 = fmaf(ca.z,  e0[2], s0);  s1 = fmaf(ca.z,  e1[2], s1);
                s0 = fmaf(ca.w,  e0[3], s0);  s1 = fmaf(ca.w,  e1[3], s1);
                s0 = fmaf(cbv.x, e0[4], s0);  s1 = fmaf(cbv.x, e1[4], s1);
                s0 = fmaf(cbv.y, e0[5], s0);  s1 = fmaf(cbv.y, e1[5], s1);
                s0 = fmaf(cbv.z, e0[6], s0);  s1 = fmaf(cbv.z, e1[6], s1);
                s0 = fmaf(cbv.w, e0[7], s0);  s1 = fmaf(cbv.w, e1[7], s1);
                if (s0 > best0) { best0 = s0; b0 = jj; }  // strict > : first idx
                if (s1 > best1) { best1 = s1; b1 = jj; }
            }
        }
        b0 += chunk * 64;
        b1 += chunk * 64;
        {   // merge 4 chunks (ascending order preserved)
            float o; int oi;
            o = __shfl_down(best0, 16, 64); oi = __shfl_down(b0, 16, 64);
            if (o > best0) { best0 = o; b0 = oi; }
            o = __shfl_down(best1, 16, 64); oi = __shfl_down(b1, 16, 64);
            if (o > best1) { best1 = o; b1 = oi; }
            o = __shfl_down(best0, 32, 64); oi = __shfl_down(b0, 32, 64);
            if (o > best0) { best0 = o; b0 = oi; }
            o = __shfl_down(best1, 32, 64); oi = __shfl_down(b1, 32, 64);
            if (o > best1) { best1 = o; b1 = oi; }
        }
        if (l < 16) {
            redS[s * TBLK + 2 * g]     = best0;
            redI[s * TBLK + 2 * g]     = b0;
            redS[s * TBLK + 2 * g + 1] = best1;
            redI[s * TBLK + 2 * g + 1] = b1;
        }
        __syncthreads();   // S1

        float bsc = redS[c];
        int   bi  = redI[c];
#pragma unroll
        for (int ww = 1; ww < 4; ++ww) {
            float v2 = redS[ww * TBLK + c];
            int   vi = redI[ww * TBLK + c];
            if (v2 > bsc) { bsc = v2; bi = vi; }
        }
        if (tid < 32) o_codes[(size_t)b * NCB * T + (size_t)i * T + t0 + tid] = (float)bi;

        // ---- zq + latents + loss: thread (r, c) ---------------------------
        {
            float ze = Pt[(base + r) * TBLK + c];
            o_lat[(size_t)b * (NCB * CD) * T + (size_t)(base + r) * T + t] = ze;
            float cv = codebook[((size_t)i * CB + bi) * CD + r];
            float dd = cv - ze;
            loss_local = fmaf(dd, dd, loss_local);
            zh[(base + r) * TBLK + c] = ze + dd;   // zq_st, reference rounding
        }
        __syncthreads();   // S2: zh(i) ready

        // ---- update future P rows: P(ip) -= G[ip][i]@zq(i) + u[ip][i] -----
        if (i < NCB - 1) {
            float zqv[CD];
#pragma unroll
            for (int j = 0; j < CD; ++j) zqv[j] = zh[(base + j) * TBLK + c];
            const float4* G4 = (const float4*)G;
            for (int ip = i + 1; ip < NCB; ++ip) {
                int p = ip * (ip - 1) / 2 + i;
                float4 g0 = G4[p * 16 + r * 2];
                float4 g1 = G4[p * 16 + r * 2 + 1];
                float acc = u[p * 8 + r];
                acc = fmaf(g0.x, zqv[0], acc);
                acc = fmaf(g0.y, zqv[1], acc);
                acc = fmaf(g0.z, zqv[2], acc);
                acc = fmaf(g0.w, zqv[3], acc);
                acc = fmaf(g1.x, zqv[4], acc);
                acc = fmaf(g1.y, zqv[5], acc);
                acc = fmaf(g1.z, zqv[6], acc);
                acc = fmaf(g1.w, zqv[7], acc);
                Pt[(ip * CD + r) * TBLK + c] -= acc;
            }
            __syncthreads();   // S3: Pt stable for next iter
        }
    }

    // ---------------- final: z_q[d] = obs[d] + sum_j out_w[j][d]@zq(j) -----
    {
        float acc[16];
#pragma unroll
        for (int m = 0; m < 16; ++m) acc[m] = obs[d0 + m];
        for (int j = 0; j < NCB; ++j) {
            float zqv[CD];
#pragma unroll
            for (int k = 0; k < CD; ++k) zqv[k] = zh[(j * CD + k) * TBLK + c];
            const float4* ow4 = (const float4*)(out_w + ((size_t)j * D + d0) * CD);
#pragma unroll 4
            for (int m = 0; m < 16; ++m) {
                float4 wa = ow4[2 * m];
                float4 wb = ow4[2 * m + 1];
                acc[m] = fmaf(wa.x, zqv[0], acc[m]);
                acc[m] = fmaf(wa.y, zqv[1], acc[m]);
                acc[m] = fmaf(wa.z, zqv[2], acc[m]);
                acc[m] = fmaf(wa.w, zqv[3], acc[m]);
                acc[m] = fmaf(wb.x, zqv[4], acc[m]);
                acc[m] = fmaf(wb.y, zqv[5], acc[m]);
                acc[m] = fmaf(wb.z, zqv[6], acc[m]);
                acc[m] = fmaf(wb.w, zqv[7], acc[m]);
            }
        }
        float* oq = o_zq + (size_t)b * D * T + (size_t)d0 * T + t;
#pragma unroll
        for (int m = 0; m < 16; ++m) oq[(size_t)m * T] = acc[m];
    }

    // ---------------- loss reduction ---------------------------------------
    {
        float w2 = loss_local;
#pragma unroll
        for (int o = 32; o > 0; o >>= 1) w2 += __shfl_down(w2, o, 64);
        if (l == 0) redw[4 + s] = w2;
        __syncthreads();
        if (tid == 0) {
            float ls = redw[4] + redw[5] + redw[6] + redw[7];
            float lsn = ls * (1.0f / (524288.0f * 9.0f));   // /(B*8*T)/NCB
            atomicAdd(&o_scal[1], lsn);
            atomicAdd(&o_scal[2], lsn);
        }
    }
}

extern "C" void kernel_launch(void* const* d_in, const int* in_sizes, int n_in,
                              void* d_out, int out_size, void* d_ws, size_t ws_size,
                              hipStream_t stream) {
    const float* x        = (const float*)d_in[0];
    const float* noise    = (const float*)d_in[1];
    const float* in_w     = (const float*)d_in[2];
    const float* in_b     = (const float*)d_in[3];
    const float* codebook = (const float*)d_in[4];
    const float* out_w    = (const float*)d_in[5];
    const float* out_b    = (const float*)d_in[6];

    float* out     = (float*)d_out;
    float* o_zq    = out + OFF_ZQ;
    float* o_scal  = out + OFF_SCAL;
    float* o_codes = out + OFF_CODES;
    float* o_lat   = out + OFF_LAT;

    float* ws  = (float*)d_ws;
    float* cbn = ws + WS_CBN;
    float* h2  = ws + WS_H2;
    float* G   = ws + WS_G;
    float* u   = ws + WS_U;
    float* obs = ws + WS_OBS;

    prep_kernel<<<(NCB * CB + 255) / 256, 256, 0, stream>>>(codebook, cbn, h2, o_scal);
    prep2_kernel<<<(NP * 64 + NP * 8 + D + 255) / 256, 256, 0, stream>>>(in_w, out_w, out_b, G, u, obs);

    dim3 grid(BB * (T / TBLK));  // 16 * 128 = 2048 blocks
    rvq_kernel<<<grid, NTHR, 0, stream>>>(x, noise, in_w, in_b, codebook, out_w,
                                          cbn, h2, G, u, obs,
                                          o_zq, o_scal, o_codes, o_lat);
}